// Round 15
// baseline (222.238 us; speedup 1.0000x reference)
//
#include <hip/hip_runtime.h>
#include <math.h>

#define Bc 4
#define Tc 512
#define Fc 512
#define Dc 256
#define RPB 8   // rows per block (ln/proj2 granularity)
#define PF 4    // A-wave k/q prefetch depth
#define CH 16   // ring chunk (timesteps)
#define RS 4    // ring slots (chunks)
#define NC (Tc / CH)

typedef float floatx4 __attribute__((ext_vector_type(4)));

__device__ __forceinline__ float wred(float v) {
#pragma unroll
  for (int off = 32; off; off >>= 1) v += __shfl_xor(v, off, 64);
  return v;
}

__device__ __forceinline__ float rl(float v, int l) {
  return __int_as_float(__builtin_amdgcn_readlane(__float_as_int(v), l));
}

// Dual wave64 sum-reduce via DPP (row_shr 1/2/4/8 + row_bcast 15/31).
__device__ __forceinline__ void wred2_dpp(float& a, float& c) {
#define DPP_STEP(ctrl, rmask)                                                 \
  {                                                                           \
    float ta = __int_as_float(__builtin_amdgcn_update_dpp(                    \
        0, __float_as_int(a), (ctrl), (rmask), 0xf, true));                   \
    float tc = __int_as_float(__builtin_amdgcn_update_dpp(                    \
        0, __float_as_int(c), (ctrl), (rmask), 0xf, true));                   \
    a += ta;                                                                  \
    c += tc;                                                                  \
  }
  DPP_STEP(0x111, 0xf)  // row_shr:1
  DPP_STEP(0x112, 0xf)  // row_shr:2
  DPP_STEP(0x114, 0xf)  // row_shr:4
  DPP_STEP(0x118, 0xf)  // row_shr:8
  DPP_STEP(0x142, 0xa)  // row_bcast:15 -> rows 1,3
  DPP_STEP(0x143, 0xc)  // row_bcast:31 -> rows 2,3
#undef DPP_STEP
  a = rl(a, 63);
  c = rl(c, 63);
}

// ---------------------------------------------------------------------------
// Kernel 0 (ln): LayerNorm all 2048 rows -> xn_g (lives in the states output
// region; scan overwrites it AFTER proj reads it — stream-ordered).
// ---------------------------------------------------------------------------
__global__ __launch_bounds__(256) void ln_kernel(
    const float* __restrict__ x, const float* __restrict__ gamma,
    const float* __restrict__ beta_ln, float* __restrict__ xn_g) {
  const int tid = threadIdx.x;
  const int wave = tid >> 6, lane = tid & 63;
  const int row0 = blockIdx.x * RPB;
#pragma unroll
  for (int rr = 0; rr < 2; ++rr) {
    const int r = wave * 2 + rr;
    const float* xr = x + (size_t)(row0 + r) * Fc;
    float4 a = *(const float4*)&xr[lane * 8];
    float4 b = *(const float4*)&xr[lane * 8 + 4];
    float s8 = a.x + a.y + a.z + a.w + b.x + b.y + b.z + b.w;
    float mu = wred(s8) * (1.0f / Fc);
    float d0 = a.x - mu, d1 = a.y - mu, d2 = a.z - mu, d3 = a.w - mu;
    float d4 = b.x - mu, d5 = b.y - mu, d6 = b.z - mu, d7 = b.w - mu;
    float sq = d0 * d0 + d1 * d1 + d2 * d2 + d3 * d3 + d4 * d4 + d5 * d5 +
               d6 * d6 + d7 * d7;
    float var = wred(sq) * (1.0f / Fc);
    float rs = rsqrtf(var + 1e-5f);
    float4 g0 = *(const float4*)&gamma[lane * 8];
    float4 g1 = *(const float4*)&gamma[lane * 8 + 4];
    float4 bl0 = *(const float4*)&beta_ln[lane * 8];
    float4 bl1 = *(const float4*)&beta_ln[lane * 8 + 4];
    float* xo = xn_g + (size_t)(row0 + r) * Fc;
    *(float4*)&xo[lane * 8] =
        make_float4(d0 * rs * g0.x + bl0.x, d1 * rs * g0.y + bl0.y,
                    d2 * rs * g0.z + bl0.z, d3 * rs * g0.w + bl0.w);
    *(float4*)&xo[lane * 8 + 4] =
        make_float4(d4 * rs * g1.x + bl1.x, d5 * rs * g1.y + bl1.y,
                    d6 * rs * g1.z + bl1.z, d7 * rs * g1.w + bl1.w);
  }
}

// ---------------------------------------------------------------------------
// Kernel 1a (proj1): weights-stationary GEMM. 512 blocks = 64 row-tiles(32)
// x 8 col-tiles(32). col-tile = bid&7 -> one 256 KB weight slice per XCD,
// L2-resident and reused by that XCD's 64 row-blocks (L2 weight traffic
// 512 MB -> ~128 MB). xn streamed via 16 KB LDS chunks. 2 blocks/CU ->
// 2 waves/SIMD interleave FMA with loads. Thread = 1 col x 4 rows.
// ---------------------------------------------------------------------------
__global__ __launch_bounds__(256, 2) void proj1_kernel(
    const float* __restrict__ xn_g, const float* __restrict__ Wk,
    const float* __restrict__ Wq, const float* __restrict__ Wv,
    const float* __restrict__ Wsc, const float* __restrict__ bsc,
    float* __restrict__ Ko, float* __restrict__ Qo, float* __restrict__ Vo,
    float* __restrict__ ysco) {
  __shared__ __align__(16) float xs[32][128];  // 16 KB f-chunk

  const int tid = threadIdx.x;
  const int bid = blockIdx.x;              // 0..511
  const int ct = bid & 7;                  // col-tile (== XCD)
  const int rt = bid >> 3;                 // row-tile 0..63
  const int row0 = rt * 32;
  const int col = ct * 32 + (tid & 31);
  const int rg = tid >> 5;                 // 0..7 -> rows rg*4..rg*4+3

  float accK[4], accQ[4], accV[4], accS[4];
#pragma unroll
  for (int r = 0; r < 4; ++r) accK[r] = accQ[r] = accV[r] = accS[r] = 0.0f;

  for (int fc = 0; fc < Fc; fc += 128) {
    __syncthreads();
    // stage xn[32 rows][128 f]: 1024 float4, 4 per thread, coalesced
#pragma unroll
    for (int m = 0; m < 4; ++m) {
      const int e = tid + 256 * m;      // 0..1023
      const int r = e >> 5;             // row 0..31
      const int c4 = e & 31;            // float4 col 0..31
      *(float4*)&xs[r][c4 * 4] =
          *(const float4*)&xn_g[(size_t)(row0 + r) * Fc + fc + c4 * 4];
    }
    __syncthreads();

    for (int f4 = 0; f4 < 128; f4 += 4) {
      float wk[4], wq[4], wv[4], ws[4];
#pragma unroll
      for (int ff = 0; ff < 4; ++ff) {
        const size_t off = (size_t)(fc + f4 + ff) * Dc + col;
        wk[ff] = Wk[off];
        wq[ff] = Wq[off];
        wv[ff] = Wv[off];
        ws[ff] = Wsc[off];
      }
#pragma unroll
      for (int r = 0; r < 4; ++r) {
        float4 xr = *(const float4*)&xs[rg * 4 + r][f4];
        accK[r] = fmaf(xr.w, wk[3], fmaf(xr.z, wk[2], fmaf(xr.y, wk[1], fmaf(xr.x, wk[0], accK[r]))));
        accQ[r] = fmaf(xr.w, wq[3], fmaf(xr.z, wq[2], fmaf(xr.y, wq[1], fmaf(xr.x, wq[0], accQ[r]))));
        accV[r] = fmaf(xr.w, wv[3], fmaf(xr.z, wv[2], fmaf(xr.y, wv[1], fmaf(xr.x, wv[0], accV[r]))));
        accS[r] = fmaf(xr.w, ws[3], fmaf(xr.z, ws[2], fmaf(xr.y, ws[1], fmaf(xr.x, ws[0], accS[r]))));
      }
    }
  }

  const float bs = bsc[col];
#pragma unroll
  for (int r = 0; r < 4; ++r) {
    const size_t row = (size_t)(row0 + rg * 4 + r);
    Ko[row * Dc + col] = fmaxf(accK[r], 0.0f);   // relu'd, unnormalized
    Qo[row * Dc + col] = fmaxf(accQ[r], 0.0f);
    Vo[row * Dc + col] = accV[r];
    ysco[row * Dc + col] = accS[r] + bs;
  }
}

// ---------------------------------------------------------------------------
// Kernel 1b (proj2): row-wide reductions + in-place normalization.
// R12 logic, but xn loaded from xn_g instead of recomputing LN.
// ---------------------------------------------------------------------------
__global__ __launch_bounds__(256) void proj2_kernel(
    const float* __restrict__ xn_g, const float* __restrict__ Wb,
    float* __restrict__ Ko, float* __restrict__ Qo, float* __restrict__ betao,
    float* __restrict__ kqo) {
  __shared__ __align__(16) float xn[RPB][Fc];
  __shared__ float red[4][32];
  __shared__ float fin[32];

  const int tid = threadIdx.x;
  const int wave = tid >> 6, lane = tid & 63;
  const int row0 = blockIdx.x * RPB;

  // stage xn rows (4096 float4, 16/thread, coalesced)
#pragma unroll
  for (int m = 0; m < 4; ++m) {
    const int e = tid + 256 * m;        // 0..1023
    const int r = e >> 7;               // row 0..7
    const int c4 = e & 127;             // float4 col
    *(float4*)&xn[r][c4 * 4] =
        *(const float4*)&xn_g[(size_t)(row0 + r) * Fc + c4 * 4];
  }
  __syncthreads();

  const int d = tid;
  float pk[RPB], pq[RPB];
#pragma unroll
  for (int r = 0; r < RPB; ++r) {
    pk[r] = Ko[(size_t)(row0 + r) * Dc + d];  // already relu'd
    pq[r] = Qo[(size_t)(row0 + r) * Dc + d];
  }
#pragma unroll
  for (int r = 0; r < RPB; ++r) {
    float p0 = wred(pk[r]);
    float p1 = wred(pq[r]);
    float p2 = wred(pk[r] * pq[r]);
    float pb = xn[r][tid] * Wb[tid] + xn[r][tid + 256] * Wb[tid + 256];
    float p3 = wred(pb);
    if (lane == 0) {
      red[wave][r * 4 + 0] = p0;
      red[wave][r * 4 + 1] = p1;
      red[wave][r * 4 + 2] = p2;
      red[wave][r * 4 + 3] = p3;
    }
  }
  __syncthreads();
  if (tid < 32) fin[tid] = red[0][tid] + red[1][tid] + red[2][tid] + red[3][tid];
  __syncthreads();

#pragma unroll
  for (int r = 0; r < RPB; ++r) {
    const size_t row = (size_t)(row0 + r);
    float invK = 1.0f / (1e-5f + fin[r * 4 + 0]);
    float invQ = 1.0f / (1e-5f + fin[r * 4 + 1]);
    Ko[row * Dc + d] = pk[r] * invK;
    Qo[row * Dc + d] = pq[r] * invQ;
  }
  if (tid < RPB) {
    const size_t row = (size_t)(row0 + tid);
    float invK = 1.0f / (1e-5f + fin[tid * 4 + 0]);
    float invQ = 1.0f / (1e-5f + fin[tid * 4 + 1]);
    betao[row] = 1.0f / (1.0f + expf(-fin[tid * 4 + 3]));
    kqo[row] = fin[tid * 4 + 2] * invK * invQ;
  }
}

// ---------------------------------------------------------------------------
// Kernel 2: producer/consumer scan (exact R12 version — best known).
// ---------------------------------------------------------------------------
__global__ __launch_bounds__(512) void scan_kernel(
    const float* __restrict__ S0, const float* __restrict__ K,
    const float* __restrict__ Q, const float* __restrict__ V,
    const float* __restrict__ ysc, const float* __restrict__ beta,
    const float* __restrict__ kq, float* __restrict__ yout,
    float* __restrict__ states) {
  __shared__ __align__(16) float ring_k[RS][CH][Dc];  // 64 KB
  __shared__ float2 ring_uy[RS][CH][4];               // 2 KB
  __shared__ int prog_a[4];
  __shared__ int prog_b[4];

  const int tid = threadIdx.x;
  const int wave = tid >> 6, lane = tid & 63;
  const int bid = blockIdx.x;               // 0..255
  const int xcd = bid & 7;                  // round-robin XCD id
  const int slot = bid >> 3;                // 0..31
  const int b = xcd >> 1;                   // 2 XCDs per batch
  const int sub = ((xcd & 1) << 5) | slot;  // 0..63 within batch
  const int i0 = sub * 4;                   // block rows: i0..i0+3

  if (tid < 4) {
    prog_a[tid] = 0;
    prog_b[tid] = 0;
  }
  __syncthreads();

  if (wave < 4) {
    // ======================= A: recurrence producer ========================
    const int i = i0 + wave;
    float4 s = *(const float4*)&S0[((size_t)(b * Dc + i)) * Dc + lane * 4];

    const float* Kb = K + (size_t)b * Tc * Dc;
    const float* Qb = Q + (size_t)b * Tc * Dc;
    const float* Vb = V + (size_t)b * Tc * Dc;
    const float* Yb = ysc + (size_t)b * Tc * Dc;
    const float* bb_p = beta + (size_t)b * Tc;
    const float* kq_p = kq + (size_t)b * Tc;

    float4 kb[PF], qb[PF];
#pragma unroll
    for (int j = 0; j < PF; ++j) {
      kb[j] = *(const float4*)&Kb[(size_t)j * Dc + lane * 4];
      qb[j] = *(const float4*)&Qb[(size_t)j * Dc + lane * 4];
    }
    const int sl = lane & 15;
    float vcur = Vb[(size_t)sl * Dc + i];
    float ycur = Yb[(size_t)sl * Dc + i];
    float bcur = bb_p[sl];
    float kqcur = kq_p[sl];

    for (int c = 0; c < NC; ++c) {
      if (c >= RS) {
        const int need = c - RS + 1;
#pragma unroll
        for (int m = 0; m < 4; ++m) {
          while (__hip_atomic_load(&prog_b[m], __ATOMIC_ACQUIRE,
                                   __HIP_MEMORY_SCOPE_WORKGROUP) < need)
            __builtin_amdgcn_s_sleep(2);
        }
      }
      const int cn = (c + 1 < NC) ? c + 1 : c;
      const int tbn = cn * CH;
      float vnxt = Vb[(size_t)(tbn + sl) * Dc + i];
      float ynxt = Yb[(size_t)(tbn + sl) * Dc + i];
      float bnxt = bb_p[tbn + sl];
      float kqnxt = kq_p[tbn + sl];

      const int r = c & (RS - 1);
      const int tb = c * CH;
#pragma unroll
      for (int j = 0; j < CH; ++j) {
        const int t = tb + j;
        const float4 k = kb[j & (PF - 1)];
        const float4 q = qb[j & (PF - 1)];
        const float vv = rl(vcur, j);
        const float yb = rl(ycur, j);
        const float bbs = rl(bcur, j);
        const float kqv = rl(kqcur, j);

        const int tn = (t + PF < Tc) ? t + PF : Tc - 1;
        kb[j & (PF - 1)] = *(const float4*)&Kb[(size_t)tn * Dc + lane * 4];
        qb[j & (PF - 1)] = *(const float4*)&Qb[(size_t)tn * Dc + lane * 4];

        float a = (s.x * k.x + s.y * k.y) + (s.z * k.z + s.w * k.w);
        float c2 = (s.x * q.x + s.y * q.y) + (s.z * q.z + s.w * q.w);
        wred2_dpp(a, c2);

        const float wcoef = bbs * (vv - a);
        s.x = fmaf(wcoef, k.x, s.x);
        s.y = fmaf(wcoef, k.y, s.y);
        s.z = fmaf(wcoef, k.z, s.z);
        s.w = fmaf(wcoef, k.w, s.w);

        if (wave == (j & 3)) *(float4*)&ring_k[r][j][lane * 4] = k;
        if (lane == 0) {
          float2 uy;
          uy.x = wcoef;
          uy.y = c2 + wcoef * kqv + yb;
          ring_uy[r][j][wave] = uy;
        }
      }
      __threadfence_block();
      __hip_atomic_store(&prog_a[wave], c + 1, __ATOMIC_RELEASE,
                         __HIP_MEMORY_SCOPE_WORKGROUP);
      vcur = vnxt;
      ycur = ynxt;
      bcur = bnxt;
      kqcur = kqnxt;
    }
  } else {
    // ======================= B: states store stream ========================
    const int wv = wave - 4;
    const int i = i0 + wv;
    float4 s = *(const float4*)&S0[((size_t)(b * Dc + i)) * Dc + lane * 4];

    for (int c = 0; c < NC; ++c) {
      const int need = c + 1;
#pragma unroll
      for (int m = 0; m < 4; ++m) {
        while (__hip_atomic_load(&prog_a[m], __ATOMIC_ACQUIRE,
                                 __HIP_MEMORY_SCOPE_WORKGROUP) < need)
          __builtin_amdgcn_s_sleep(2);
      }

      const int r = c & (RS - 1);
      const int tb = c * CH;
#pragma unroll
      for (int j = 0; j < CH; ++j) {
        const float2 uy = ring_uy[r][j][wv];
        const float4 k = *(const float4*)&ring_k[r][j][lane * 4];
        s.x = fmaf(uy.x, k.x, s.x);
        s.y = fmaf(uy.x, k.y, s.y);
        s.z = fmaf(uy.x, k.z, s.z);
        s.w = fmaf(uy.x, k.w, s.w);
        floatx4 sv;
        sv.x = s.x; sv.y = s.y; sv.z = s.z; sv.w = s.w;
        __builtin_nontemporal_store(
            sv, (floatx4*)&states[(((size_t)b * Tc + tb + j) * Dc + i) * Dc +
                                  lane * 4]);
        if (lane == 0) yout[((size_t)b * Tc + tb + j) * Dc + i] = uy.y;
      }
      __threadfence_block();
      __hip_atomic_store(&prog_b[wv], c + 1, __ATOMIC_RELEASE,
                         __HIP_MEMORY_SCOPE_WORKGROUP);
    }
  }
}

// ---------------------------------------------------------------------------
extern "C" void kernel_launch(void* const* d_in, const int* in_sizes, int n_in,
                              void* d_out, int out_size, void* d_ws,
                              size_t ws_size, hipStream_t stream) {
  const float* x = (const float*)d_in[0];
  const float* S0 = (const float*)d_in[1];
  const float* Wk = (const float*)d_in[2];
  const float* Wq = (const float*)d_in[3];
  const float* Wv = (const float*)d_in[4];
  const float* Wb = (const float*)d_in[5];
  const float* gamma = (const float*)d_in[6];
  const float* beta_ln = (const float*)d_in[7];
  const float* Wsc = (const float*)d_in[8];
  const float* bsc = (const float*)d_in[9];

  float* out = (float*)d_out;
  float* yout = out;                              // [B,T,D]
  float* states = out + (size_t)Bc * Tc * Dc;     // [B,T,D,D]

  const size_t BTD = (size_t)Bc * Tc * Dc;
  float* ws = (float*)d_ws;
  float* K = ws;
  float* Q = K + BTD;
  float* V = Q + BTD;
  float* ysc = V + BTD;
  float* beta = ysc + BTD;
  float* kq = beta + (size_t)Bc * Tc;

  // xn scratch lives in the states output region (4 MB of 512 MB); scan
  // overwrites it only after proj kernels complete (stream-ordered).
  float* xn_g = states;

  ln_kernel<<<(Bc * Tc) / RPB, 256, 0, stream>>>(x, gamma, beta_ln, xn_g);
  proj1_kernel<<<512, 256, 0, stream>>>(xn_g, Wk, Wq, Wv, Wsc, bsc, K, Q, V,
                                        ysc);
  proj2_kernel<<<(Bc * Tc) / RPB, 256, 0, stream>>>(xn_g, Wb, K, Q, beta, kq);
  scan_kernel<<<(Bc * Dc) / 4, 512, 0, stream>>>(S0, K, Q, V, ysc, beta, kq,
                                                 yout, states);
}

// Round 16
// 151.212 us; speedup vs baseline: 1.4697x; 1.4697x over previous
//
#include <hip/hip_runtime.h>
#include <math.h>

#define Bc 4
#define Tc 512
#define Fc 512
#define Dc 256
#define RPB 8   // rows per block (proj2 / LN granularity)
#define PF 4    // A-wave k/q prefetch depth
#define CH 16   // ring chunk (timesteps)
#define RS 4    // ring slots (chunks)
#define NC (Tc / CH)

typedef float floatx4 __attribute__((ext_vector_type(4)));

__device__ __forceinline__ float wred(float v) {
#pragma unroll
  for (int off = 32; off; off >>= 1) v += __shfl_xor(v, off, 64);
  return v;
}

__device__ __forceinline__ float rl(float v, int l) {
  return __int_as_float(__builtin_amdgcn_readlane(__float_as_int(v), l));
}

// Dual wave64 sum-reduce via DPP (row_shr 1/2/4/8 + row_bcast 15/31).
__device__ __forceinline__ void wred2_dpp(float& a, float& c) {
#define DPP_STEP(ctrl, rmask)                                                 \
  {                                                                           \
    float ta = __int_as_float(__builtin_amdgcn_update_dpp(                    \
        0, __float_as_int(a), (ctrl), (rmask), 0xf, true));                   \
    float tc = __int_as_float(__builtin_amdgcn_update_dpp(                    \
        0, __float_as_int(c), (ctrl), (rmask), 0xf, true));                   \
    a += ta;                                                                  \
    c += tc;                                                                  \
  }
  DPP_STEP(0x111, 0xf)  // row_shr:1
  DPP_STEP(0x112, 0xf)  // row_shr:2
  DPP_STEP(0x114, 0xf)  // row_shr:4
  DPP_STEP(0x118, 0xf)  // row_shr:8
  DPP_STEP(0x142, 0xa)  // row_bcast:15 -> rows 1,3
  DPP_STEP(0x143, 0xc)  // row_bcast:31 -> rows 2,3
#undef DPP_STEP
  a = rl(a, 63);
  c = rl(c, 63);
}

// Parallel 4-flag poll: issue 4 RELAXED loads back-to-back (independent),
// one combined exit test; __threadfence_block() after exit provides the
// acquire ordering. Replaces 4 sequential dependent acquire-poll loops
// (~480 cy/chunk -> ~130 cy/chunk).
__device__ __forceinline__ void wait4_ge(int* f, int need) {
  while (true) {
    int p0 = __hip_atomic_load(&f[0], __ATOMIC_RELAXED,
                               __HIP_MEMORY_SCOPE_WORKGROUP);
    int p1 = __hip_atomic_load(&f[1], __ATOMIC_RELAXED,
                               __HIP_MEMORY_SCOPE_WORKGROUP);
    int p2 = __hip_atomic_load(&f[2], __ATOMIC_RELAXED,
                               __HIP_MEMORY_SCOPE_WORKGROUP);
    int p3 = __hip_atomic_load(&f[3], __ATOMIC_RELAXED,
                               __HIP_MEMORY_SCOPE_WORKGROUP);
    if (p0 >= need && p1 >= need && p2 >= need && p3 >= need) break;
    __builtin_amdgcn_s_sleep(2);
  }
  __threadfence_block();  // acquire: order subsequent LDS reads after flags
}

// Shared LN helper: computes xn for rows [row0, row0+8) into xnL[8][Fc].
__device__ __forceinline__ void ln_rows(const float* __restrict__ x,
                                        const float* __restrict__ gamma,
                                        const float* __restrict__ beta_ln,
                                        int row0, int wave, int lane,
                                        float (*xnL)[Fc]) {
#pragma unroll
  for (int rr = 0; rr < 2; ++rr) {
    const int r = wave * 2 + rr;
    const float* xr = x + (size_t)(row0 + r) * Fc;
    float4 a = *(const float4*)&xr[lane * 8];
    float4 b = *(const float4*)&xr[lane * 8 + 4];
    float s8 = a.x + a.y + a.z + a.w + b.x + b.y + b.z + b.w;
    float mu = wred(s8) * (1.0f / Fc);
    float d0 = a.x - mu, d1 = a.y - mu, d2 = a.z - mu, d3 = a.w - mu;
    float d4 = b.x - mu, d5 = b.y - mu, d6 = b.z - mu, d7 = b.w - mu;
    float sq = d0 * d0 + d1 * d1 + d2 * d2 + d3 * d3 + d4 * d4 + d5 * d5 +
               d6 * d6 + d7 * d7;
    float var = wred(sq) * (1.0f / Fc);
    float rs = rsqrtf(var + 1e-5f);
    float4 g0 = *(const float4*)&gamma[lane * 8];
    float4 g1 = *(const float4*)&gamma[lane * 8 + 4];
    float4 bl0 = *(const float4*)&beta_ln[lane * 8];
    float4 bl1 = *(const float4*)&beta_ln[lane * 8 + 4];
    float4 o0 = make_float4(d0 * rs * g0.x + bl0.x, d1 * rs * g0.y + bl0.y,
                            d2 * rs * g0.z + bl0.z, d3 * rs * g0.w + bl0.w);
    float4 o1 = make_float4(d4 * rs * g1.x + bl1.x, d5 * rs * g1.y + bl1.y,
                            d6 * rs * g1.z + bl1.z, d7 * rs * g1.w + bl1.w);
    *(float4*)&xnL[r][lane * 8] = o0;
    *(float4*)&xnL[r][lane * 8 + 4] = o1;
  }
}

// ---------------------------------------------------------------------------
// Kernel 1a (proj1): GEMM part, split-D (exact R12 version — best known).
// ---------------------------------------------------------------------------
__global__ __launch_bounds__(256, 2) void proj1_kernel(
    const float* __restrict__ x, const float* __restrict__ Wk,
    const float* __restrict__ Wq, const float* __restrict__ Wv,
    const float* __restrict__ gamma, const float* __restrict__ beta_ln,
    const float* __restrict__ Wsc, const float* __restrict__ bsc,
    float* __restrict__ Ko, float* __restrict__ Qo, float* __restrict__ Vo,
    float* __restrict__ ysco) {
  __shared__ __align__(16) float xn[RPB][Fc];  // 16 KB

  const int tid = threadIdx.x;
  const int wave = tid >> 6, lane = tid & 63;
  const int bid = blockIdx.x;          // 0..511
  const int half = bid & 1;            // col half (== xcd parity)
  const int row0 = (bid >> 1) * RPB;   // 8-row tile
  const int col = half * 128 + (tid & 127);
  const int rg = tid >> 7;             // 0/1 -> rows rg*4 .. rg*4+3

  ln_rows(x, gamma, beta_ln, row0, wave, lane, xn);
  __syncthreads();

  float accK[4], accQ[4], accV[4], accS[4];
#pragma unroll
  for (int r = 0; r < 4; ++r) accK[r] = accQ[r] = accV[r] = accS[r] = 0.0f;

  for (int f = 0; f < Fc; f += 4) {
    float wk[4], wq[4], wv[4], ws[4];
#pragma unroll
    for (int ff = 0; ff < 4; ++ff) {
      wk[ff] = Wk[(size_t)(f + ff) * Dc + col];
      wq[ff] = Wq[(size_t)(f + ff) * Dc + col];
      wv[ff] = Wv[(size_t)(f + ff) * Dc + col];
      ws[ff] = Wsc[(size_t)(f + ff) * Dc + col];
    }
#pragma unroll
    for (int r = 0; r < 4; ++r) {
      float4 xr = *(const float4*)&xn[rg * 4 + r][f];
      accK[r] = fmaf(xr.w, wk[3], fmaf(xr.z, wk[2], fmaf(xr.y, wk[1], fmaf(xr.x, wk[0], accK[r]))));
      accQ[r] = fmaf(xr.w, wq[3], fmaf(xr.z, wq[2], fmaf(xr.y, wq[1], fmaf(xr.x, wq[0], accQ[r]))));
      accV[r] = fmaf(xr.w, wv[3], fmaf(xr.z, wv[2], fmaf(xr.y, wv[1], fmaf(xr.x, wv[0], accV[r]))));
      accS[r] = fmaf(xr.w, ws[3], fmaf(xr.z, ws[2], fmaf(xr.y, ws[1], fmaf(xr.x, ws[0], accS[r]))));
    }
  }

  const float bs = bsc[col];
#pragma unroll
  for (int r = 0; r < 4; ++r) {
    const size_t row = (size_t)(row0 + rg * 4 + r);
    Ko[row * Dc + col] = fmaxf(accK[r], 0.0f);   // relu'd, unnormalized
    Qo[row * Dc + col] = fmaxf(accQ[r], 0.0f);
    Vo[row * Dc + col] = accV[r];
    ysco[row * Dc + col] = accS[r] + bs;
  }
}

// ---------------------------------------------------------------------------
// Kernel 1b (proj2): row-wide reductions + in-place normalization
// (exact R12 version).
// ---------------------------------------------------------------------------
__global__ __launch_bounds__(256) void proj2_kernel(
    const float* __restrict__ x, const float* __restrict__ Wb,
    const float* __restrict__ gamma, const float* __restrict__ beta_ln,
    float* __restrict__ Ko, float* __restrict__ Qo, float* __restrict__ betao,
    float* __restrict__ kqo) {
  __shared__ __align__(16) float xn[RPB][Fc];
  __shared__ float red[4][32];
  __shared__ float fin[32];

  const int tid = threadIdx.x;
  const int wave = tid >> 6, lane = tid & 63;
  const int row0 = blockIdx.x * RPB;

  ln_rows(x, gamma, beta_ln, row0, wave, lane, xn);
  __syncthreads();

  const int d = tid;
  float pk[RPB], pq[RPB];
#pragma unroll
  for (int r = 0; r < RPB; ++r) {
    pk[r] = Ko[(size_t)(row0 + r) * Dc + d];  // already relu'd
    pq[r] = Qo[(size_t)(row0 + r) * Dc + d];
  }
#pragma unroll
  for (int r = 0; r < RPB; ++r) {
    float p0 = wred(pk[r]);
    float p1 = wred(pq[r]);
    float p2 = wred(pk[r] * pq[r]);
    float pb = xn[r][tid] * Wb[tid] + xn[r][tid + 256] * Wb[tid + 256];
    float p3 = wred(pb);
    if (lane == 0) {
      red[wave][r * 4 + 0] = p0;
      red[wave][r * 4 + 1] = p1;
      red[wave][r * 4 + 2] = p2;
      red[wave][r * 4 + 3] = p3;
    }
  }
  __syncthreads();
  if (tid < 32) fin[tid] = red[0][tid] + red[1][tid] + red[2][tid] + red[3][tid];
  __syncthreads();

#pragma unroll
  for (int r = 0; r < RPB; ++r) {
    const size_t row = (size_t)(row0 + r);
    float invK = 1.0f / (1e-5f + fin[r * 4 + 0]);
    float invQ = 1.0f / (1e-5f + fin[r * 4 + 1]);
    Ko[row * Dc + d] = pk[r] * invK;
    Qo[row * Dc + d] = pq[r] * invQ;
  }
  if (tid < RPB) {
    const size_t row = (size_t)(row0 + tid);
    float invK = 1.0f / (1e-5f + fin[tid * 4 + 0]);
    float invQ = 1.0f / (1e-5f + fin[tid * 4 + 1]);
    betao[row] = 1.0f / (1.0f + expf(-fin[tid * 4 + 3]));
    kqo[row] = fin[tid * 4 + 2] * invK * invQ;
  }
}

// ---------------------------------------------------------------------------
// Kernel 2: producer/consumer scan — exact R12 structure (nt stores, ring,
// pure-load A). ONE change: both flag-poll sites use wait4_ge (parallel
// relaxed polls + fence) instead of 4 sequential dependent acquire loops.
// ---------------------------------------------------------------------------
__global__ __launch_bounds__(512) void scan_kernel(
    const float* __restrict__ S0, const float* __restrict__ K,
    const float* __restrict__ Q, const float* __restrict__ V,
    const float* __restrict__ ysc, const float* __restrict__ beta,
    const float* __restrict__ kq, float* __restrict__ yout,
    float* __restrict__ states) {
  __shared__ __align__(16) float ring_k[RS][CH][Dc];  // 64 KB
  __shared__ float2 ring_uy[RS][CH][4];               // 2 KB
  __shared__ int prog_a[4];
  __shared__ int prog_b[4];

  const int tid = threadIdx.x;
  const int wave = tid >> 6, lane = tid & 63;
  const int bid = blockIdx.x;               // 0..255
  const int xcd = bid & 7;                  // round-robin XCD id
  const int slot = bid >> 3;                // 0..31
  const int b = xcd >> 1;                   // 2 XCDs per batch
  const int sub = ((xcd & 1) << 5) | slot;  // 0..63 within batch
  const int i0 = sub * 4;                   // block rows: i0..i0+3

  if (tid < 4) {
    prog_a[tid] = 0;
    prog_b[tid] = 0;
  }
  __syncthreads();

  if (wave < 4) {
    // ======================= A: recurrence producer ========================
    const int i = i0 + wave;
    float4 s = *(const float4*)&S0[((size_t)(b * Dc + i)) * Dc + lane * 4];

    const float* Kb = K + (size_t)b * Tc * Dc;
    const float* Qb = Q + (size_t)b * Tc * Dc;
    const float* Vb = V + (size_t)b * Tc * Dc;
    const float* Yb = ysc + (size_t)b * Tc * Dc;
    const float* bb_p = beta + (size_t)b * Tc;
    const float* kq_p = kq + (size_t)b * Tc;

    float4 kb[PF], qb[PF];
#pragma unroll
    for (int j = 0; j < PF; ++j) {
      kb[j] = *(const float4*)&Kb[(size_t)j * Dc + lane * 4];
      qb[j] = *(const float4*)&Qb[(size_t)j * Dc + lane * 4];
    }
    const int sl = lane & 15;
    float vcur = Vb[(size_t)sl * Dc + i];
    float ycur = Yb[(size_t)sl * Dc + i];
    float bcur = bb_p[sl];
    float kqcur = kq_p[sl];

    for (int c = 0; c < NC; ++c) {
      if (c >= RS) wait4_ge(prog_b, c - RS + 1);

      const int cn = (c + 1 < NC) ? c + 1 : c;
      const int tbn = cn * CH;
      float vnxt = Vb[(size_t)(tbn + sl) * Dc + i];
      float ynxt = Yb[(size_t)(tbn + sl) * Dc + i];
      float bnxt = bb_p[tbn + sl];
      float kqnxt = kq_p[tbn + sl];

      const int r = c & (RS - 1);
      const int tb = c * CH;
#pragma unroll
      for (int j = 0; j < CH; ++j) {
        const int t = tb + j;
        const float4 k = kb[j & (PF - 1)];
        const float4 q = qb[j & (PF - 1)];
        const float vv = rl(vcur, j);
        const float yb = rl(ycur, j);
        const float bbs = rl(bcur, j);
        const float kqv = rl(kqcur, j);

        const int tn = (t + PF < Tc) ? t + PF : Tc - 1;
        kb[j & (PF - 1)] = *(const float4*)&Kb[(size_t)tn * Dc + lane * 4];
        qb[j & (PF - 1)] = *(const float4*)&Qb[(size_t)tn * Dc + lane * 4];

        float a = (s.x * k.x + s.y * k.y) + (s.z * k.z + s.w * k.w);
        float c2 = (s.x * q.x + s.y * q.y) + (s.z * q.z + s.w * q.w);
        wred2_dpp(a, c2);

        const float wcoef = bbs * (vv - a);
        s.x = fmaf(wcoef, k.x, s.x);
        s.y = fmaf(wcoef, k.y, s.y);
        s.z = fmaf(wcoef, k.z, s.z);
        s.w = fmaf(wcoef, k.w, s.w);

        if (wave == (j & 3)) *(float4*)&ring_k[r][j][lane * 4] = k;
        if (lane == 0) {
          float2 uy;
          uy.x = wcoef;
          uy.y = c2 + wcoef * kqv + yb;
          ring_uy[r][j][wave] = uy;
        }
      }
      __threadfence_block();
      __hip_atomic_store(&prog_a[wave], c + 1, __ATOMIC_RELEASE,
                         __HIP_MEMORY_SCOPE_WORKGROUP);
      vcur = vnxt;
      ycur = ynxt;
      bcur = bnxt;
      kqcur = kqnxt;
    }
  } else {
    // ======================= B: states store stream ========================
    const int wv = wave - 4;
    const int i = i0 + wv;
    float4 s = *(const float4*)&S0[((size_t)(b * Dc + i)) * Dc + lane * 4];

    for (int c = 0; c < NC; ++c) {
      wait4_ge(prog_a, c + 1);

      const int r = c & (RS - 1);
      const int tb = c * CH;
#pragma unroll
      for (int j = 0; j < CH; ++j) {
        const float2 uy = ring_uy[r][j][wv];
        const float4 k = *(const float4*)&ring_k[r][j][lane * 4];
        s.x = fmaf(uy.x, k.x, s.x);
        s.y = fmaf(uy.x, k.y, s.y);
        s.z = fmaf(uy.x, k.z, s.z);
        s.w = fmaf(uy.x, k.w, s.w);
        floatx4 sv;
        sv.x = s.x; sv.y = s.y; sv.z = s.z; sv.w = s.w;
        __builtin_nontemporal_store(
            sv, (floatx4*)&states[(((size_t)b * Tc + tb + j) * Dc + i) * Dc +
                                  lane * 4]);
        if (lane == 0) yout[((size_t)b * Tc + tb + j) * Dc + i] = uy.y;
      }
      __threadfence_block();
      __hip_atomic_store(&prog_b[wv], c + 1, __ATOMIC_RELEASE,
                         __HIP_MEMORY_SCOPE_WORKGROUP);
    }
  }
}

// ---------------------------------------------------------------------------
extern "C" void kernel_launch(void* const* d_in, const int* in_sizes, int n_in,
                              void* d_out, int out_size, void* d_ws,
                              size_t ws_size, hipStream_t stream) {
  const float* x = (const float*)d_in[0];
  const float* S0 = (const float*)d_in[1];
  const float* Wk = (const float*)d_in[2];
  const float* Wq = (const float*)d_in[3];
  const float* Wv = (const float*)d_in[4];
  const float* Wb = (const float*)d_in[5];
  const float* gamma = (const float*)d_in[6];
  const float* beta_ln = (const float*)d_in[7];
  const float* Wsc = (const float*)d_in[8];
  const float* bsc = (const float*)d_in[9];

  float* out = (float*)d_out;
  float* yout = out;                              // [B,T,D]
  float* states = out + (size_t)Bc * Tc * Dc;     // [B,T,D,D]

  const size_t BTD = (size_t)Bc * Tc * Dc;
  float* ws = (float*)d_ws;
  float* K = ws;
  float* Q = K + BTD;
  float* V = Q + BTD;
  float* ysc = V + BTD;
  float* beta = ysc + BTD;
  float* kq = beta + (size_t)Bc * Tc;

  proj1_kernel<<<(Bc * Tc) / RPB * 2, 256, 0, stream>>>(
      x, Wk, Wq, Wv, gamma, beta_ln, Wsc, bsc, K, Q, V, ysc);
  proj2_kernel<<<(Bc * Tc) / RPB, 256, 0, stream>>>(x, Wb, gamma, beta_ln, K,
                                                    Q, beta, kq);
  scan_kernel<<<(Bc * Dc) / 4, 512, 0, stream>>>(S0, K, Q, V, ysc, beta, kq,
                                                 yout, states);
}